// Round 12
// baseline (74.055 us; speedup 1.0000x reference)
//
#include <hip/hip_runtime.h>
#include <hip/hip_bf16.h>
#include <math.h>

#define NFEAT 17
#define DN 20
#define OCH 32
#define H1 500
#define H2 60

// Only d[0..3] are nonzero: g-rows are unit-norm positive => y=h[f] <= 2; grid
// step 2.632; max-normalized Gaussian at k>=4 underflows fp32 to 0.
#define DK 4

// ws float offsets
#define OFF_D      0         // 8192*4 = 32768 (compact dmat [n][4])
#define OFF_MOMP   32768     // 14 * NBW = 3584 (transposed [u][block])
#define OFF_WQ     36352     // 288
#define OFF_WP     36640     // 288
#define OFF_MT     36928     // 32*14 = 448 (per-channel tap moments T[4],M[10])
#define OFF_U4     37376     // 500*4 = 2000 (compact U)
#define OFF_CST    39376     // 512
#define OFF_W2T    39888     // 500*64 (padded w2 transpose [o][64])

#define NBW 256  // momp block-stride (capacity); nbd = ceil(8192/32) = 256

// ---------- K1: fused g-gather(8 thr/node) + distribute(4-pt) + moment partials ----------
// Tail blocks: 8x LDS-tiled w2 transpose + 1x {wq/wp tables + tap-moment MT}.
#define TB1 256
#define NPB1 32
__global__ __launch_bounds__(TB1) void k_gd(const float* __restrict__ oe,
                                            const int* __restrict__ nei,
                                            const int* __restrict__ eai,
                                            const float* __restrict__ w2,
                                            const float* __restrict__ convw,
                                            float* __restrict__ dmat,
                                            float* __restrict__ momp,
                                            float* __restrict__ w2t,
                                            float* __restrict__ wq,
                                            float* __restrict__ wp,
                                            float* __restrict__ MT, int n_node) {
  int nbd = (n_node + NPB1 - 1) / NPB1;
  int tid = threadIdx.x;
  if ((int)blockIdx.x >= nbd) {
    int tb = blockIdx.x - nbd;
    if (tb < 8) {
      // coalesced transpose of one 64-col slab: w2[60][500] -> w2t[500][64]
      __shared__ float sT[64][61];
      int o0 = tb * 64;
      int lo = tid & 63, jr = tid >> 6;
      for (int j = jr; j < H2; j += 4)
        if (o0 + lo < H1) sT[lo][j] = w2[(size_t)j * H1 + o0 + lo];
      __syncthreads();
      int jj = tid & 63, orr = tid >> 6;
      for (int ol = orr; ol < 64; ol += 4) {
        int o = o0 + ol;
        if (o < H1) w2t[(size_t)o * 64 + jj] = (jj < H2) ? sT[ol][jj] : 0.f;
      }
    } else {
      // wq/wp tap tables + per-channel tap-moment sums T[4], M[10]
      __shared__ float swqL[288], swpL[288];
      __shared__ float MTs[OCH][14];
      if (tid < OCH) {
        int c = tid;
        float w[3][3];
#pragma unroll
        for (int p = 0; p < 3; ++p)
#pragma unroll
          for (int q = 0; q < 3; ++q) w[p][q] = convw[c * 9 + p * 3 + q];
#pragma unroll
        for (int p = 0; p < 3; ++p) {
          float v0 = w[p][1] + w[p][2], v1 = w[p][0] + w[p][1] + w[p][2], v2 = w[p][0] + w[p][1];
          wq[(c * 3 + p) * 3 + 0] = v0; swqL[(c * 3 + p) * 3 + 0] = v0;
          wq[(c * 3 + p) * 3 + 1] = v1; swqL[(c * 3 + p) * 3 + 1] = v1;
          wq[(c * 3 + p) * 3 + 2] = v2; swqL[(c * 3 + p) * 3 + 2] = v2;
        }
#pragma unroll
        for (int q = 0; q < 3; ++q) {
          float v0 = w[1][q] + w[2][q], v1 = w[0][q] + w[1][q] + w[2][q], v2 = w[0][q] + w[1][q];
          wp[(c * 3 + q) * 3 + 0] = v0; swpL[(c * 3 + q) * 3 + 0] = v0;
          wp[(c * 3 + q) * 3 + 1] = v1; swpL[(c * 3 + q) * 3 + 1] = v1;
          wp[(c * 3 + q) * 3 + 2] = v2; swpL[(c * 3 + q) * 3 + 2] = v2;
        }
      }
      for (int idx = tid; idx < OCH * 14; idx += TB1) MTs[idx / 14][idx % 14] = 0.f;
      __syncthreads();
      int c = tid & 31, grp = tid >> 5;   // 8 position groups
      float wqr[3][3], wpr[3][3];
#pragma unroll
      for (int p = 0; p < 3; ++p)
#pragma unroll
        for (int k = 0; k < 3; ++k) {
          wqr[p][k] = swqL[(c * 3 + p) * 3 + k];
          wpr[p][k] = swpL[(c * 3 + p) * 3 + k];
        }
      float T0 = 0, T1 = 0, T2 = 0, T3 = 0;
      float M0 = 0, M1 = 0, M2 = 0, M3 = 0, M4 = 0, M5 = 0, M6 = 0, M7 = 0, M8 = 0, M9 = 0;
      for (int pos = grp; pos < DN * DN; pos += 8) {
        int i = pos / DN, j = pos - (pos / DN) * DN;
        int icls = (i == 0) ? 0 : ((i == DN - 1) ? 2 : 1);
        int jcls = (j == 0) ? 0 : ((j == DN - 1) ? 2 : 1);
        float t0 = 0, t1 = 0, t2 = 0, t3 = 0;
        {
          int p;
          p = 0 - i + 1; if ((unsigned)p <= 2u) t0 += wqr[p][jcls];
          p = 1 - i + 1; if ((unsigned)p <= 2u) t1 += wqr[p][jcls];
          p = 2 - i + 1; if ((unsigned)p <= 2u) t2 += wqr[p][jcls];
          p = 3 - i + 1; if ((unsigned)p <= 2u) t3 += wqr[p][jcls];
          p = 0 - j + 1; if ((unsigned)p <= 2u) t0 += wpr[p][icls];
          p = 1 - j + 1; if ((unsigned)p <= 2u) t1 += wpr[p][icls];
          p = 2 - j + 1; if ((unsigned)p <= 2u) t2 += wpr[p][icls];
          p = 3 - j + 1; if ((unsigned)p <= 2u) t3 += wpr[p][icls];
        }
        T0 += t0; T1 += t1; T2 += t2; T3 += t3;
        M0 += t0 * t0; M1 += t0 * t1; M2 += t0 * t2; M3 += t0 * t3;
        M4 += t1 * t1; M5 += t1 * t2; M6 += t1 * t3;
        M7 += t2 * t2; M8 += t2 * t3; M9 += t3 * t3;
      }
      atomicAdd(&MTs[c][0], T0); atomicAdd(&MTs[c][1], T1);
      atomicAdd(&MTs[c][2], T2); atomicAdd(&MTs[c][3], T3);
      atomicAdd(&MTs[c][4], M0); atomicAdd(&MTs[c][5], M1);
      atomicAdd(&MTs[c][6], M2); atomicAdd(&MTs[c][7], M3);
      atomicAdd(&MTs[c][8], M4); atomicAdd(&MTs[c][9], M5);
      atomicAdd(&MTs[c][10], M6); atomicAdd(&MTs[c][11], M7);
      atomicAdd(&MTs[c][12], M8); atomicAdd(&MTs[c][13], M9);
      __syncthreads();
      for (int idx = tid; idx < OCH * 14; idx += TB1) MT[idx] = MTs[idx / 14][idx % 14];
    }
    return;
  }

  // ---- node blocks: 8 threads/node (element half = t>>2, atom m = t&3) ----
  __shared__ float dls[NPB1][4];
  int nl = tid >> 3, t = tid & 7;
  int half = t >> 2, m = t & 3;
  int n = blockIdx.x * NPB1 + nl;

  float a[NFEAT];
#pragma unroll
  for (int f = 0; f < NFEAT; ++f) a[f] = 0.f;
  if (n < n_node) {
    int e = eai[(size_t)n * 2 + half];
    int at = nei[(size_t)e * 4 + m];
    const float* row = oe + (size_t)at * NFEAT;
#pragma unroll
    for (int f = 0; f < NFEAT; ++f) a[f] = row[f];
  }
  // sum 4 atoms (lanes m=0..3 within element)
#pragma unroll
  for (int f = 0; f < NFEAT; ++f) {
    a[f] += __shfl_xor(a[f], 1);
    a[f] += __shfl_xor(a[f], 2);
  }
  // normalize element mean, then sum the two elements (xor 4)
  float nrm = 0.f;
#pragma unroll
  for (int f = 0; f < NFEAT; ++f) { float v = a[f] * 0.25f; a[f] = v; nrm += v * v; }
  float inv = (n < n_node) ? 1.0f / sqrtf(nrm) : 0.f;
  float h[NFEAT];
#pragma unroll
  for (int f = 0; f < NFEAT; ++f) {
    float g = a[f] * inv;
    h[f] = g + __shfl_xor(g, 4);
  }

  const float step = 50.0f / 19.0f;
  const float inv2 = 1.0f / (2.0f * 0.3f * 0.3f);
  float s0 = 0.f, s1 = 0.f, s2 = 0.f, s3 = 0.f;
  for (int f = t; f < NFEAT; f += 8) {
    float y = h[f];
    if (!(y > 0.0f && y < 110.0f)) continue;
    float t0 = -y, t1 = step - y, t2 = 2.f * step - y, t3 = 3.f * step - y;
    float e0 = __expf(-t0 * t0 * inv2);
    float e1 = __expf(-t1 * t1 * inv2);
    float e2 = __expf(-t2 * t2 * inv2);
    float e3 = __expf(-t3 * t3 * inv2);
    float mx = fmaxf(fmaxf(e0, e1), fmaxf(e2, e3));
    if (mx > 0.f) {
      float im = 1.0f / mx;
      s0 += e0 * im; s1 += e1 * im; s2 += e2 * im; s3 += e3 * im;
    }
  }
#pragma unroll
  for (int d = 1; d <= 4; d <<= 1) {
    s0 += __shfl_xor(s0, d); s1 += __shfl_xor(s1, d);
    s2 += __shfl_xor(s2, d); s3 += __shfl_xor(s3, d);
  }
  float smax = fmaxf(fmaxf(s0, s1), fmaxf(s2, s3));
  float ism = (smax > 0.f) ? 1.0f / smax : 1.0f;
  if (t == 0) {
    float d0 = s0 * ism, d1 = s1 * ism, d2 = s2 * ism, d3 = s3 * ism;
    dls[nl][0] = d0; dls[nl][1] = d1; dls[nl][2] = d2; dls[nl][3] = d3;
    if (n < n_node)
      *(float4*)(dmat + (size_t)n * DK) = make_float4(d0, d1, d2, d3);
  }
  __syncthreads();

  // per-block moment partials: 10 tri P(4x4) + 4 sums -> momp[u][block]
  if (tid < 14) {
    int u = tid;
    float acc = 0.f;
    if (u < 10) {
      int aa = 0, rem = u;
      while (rem >= DK - aa) { rem -= DK - aa; ++aa; }
      int bb = aa + rem;
      for (int l = 0; l < NPB1; ++l) acc += dls[l][aa] * dls[l][bb];
    } else {
      int aa = u - 10;
      for (int l = 0; l < NPB1; ++l) acc += dls[l][aa];
    }
    momp[(size_t)u * NBW + blockIdx.x] = acc;
  }
}

// ---------- K2: buildU with integrated BN-coef (momp+MT -> acoef/coefc locally) ----------
__global__ __launch_bounds__(512) void k_buildU(const float* __restrict__ w1,
                                                const float* __restrict__ b1,
                                                const float* __restrict__ convb,
                                                const float* __restrict__ gamma,
                                                const float* __restrict__ beta,
                                                const float* __restrict__ wq,
                                                const float* __restrict__ wp,
                                                const float* __restrict__ momp,
                                                const float* __restrict__ MT,
                                                int nbd, int n_node,
                                                float* __restrict__ U4,
                                                float* __restrict__ Cst) {
  int o = blockIdx.x;
  int tid = threadIdx.x;
  __shared__ float sW[OCH * DN * 21];                 // 53.76 KB
  __shared__ float rowRS[OCH][DN], colCS[OCH][DN];
  __shared__ float rowRW[3][OCH][DN], colCW[3][OCH][DN];
  __shared__ float swq[288], swp[288], sac[OCH], scc[OCH], red[OCH];
  __shared__ float mred[14][4], phat[10], S4[4];
  for (int idx = tid; idx < 288; idx += 512) { swq[idx] = wq[idx]; swp[idx] = wp[idx]; }
  // momp reduce: 56 threads, each sums one quarter of one u-row
  if (tid < 56) {
    int u = tid >> 2, part = tid & 3;
    int b0 = part * 64, bend = (b0 + 64 < nbd) ? b0 + 64 : nbd;
    float acc = 0.f;
    const float* mp = momp + (size_t)u * NBW;
    for (int b = b0; b < bend; ++b) acc += mp[b];
    mred[u][part] = acc;
  }
  __syncthreads();
  if (tid < 14) {
    float v = mred[tid][0] + mred[tid][1] + mred[tid][2] + mred[tid][3];
    if (tid < 10) {
      int aa = 0, rem = tid;
      while (rem >= DK - aa) { rem -= DK - aa; ++aa; }
      int bb = aa + rem;
      phat[tid] = (aa == bb ? 1.f : 2.f) * v;
    } else {
      S4[tid - 10] = v;
    }
  }
  __syncthreads();
  if (tid < OCH) {
    int c = tid;
    const float* mt = MT + c * 14;
    float q2 = mt[0] * S4[0] + mt[1] * S4[1] + mt[2] * S4[2] + mt[3] * S4[3];
    float q1 = 0.f;
#pragma unroll
    for (int u = 0; u < 10; ++u) q1 += mt[4 + u] * phat[u];
    float b_c = convb[c];
    float Nt = (float)n_node * 400.f;
    float S1 = q2 + Nt * b_c;
    float S2 = q1 + 2.f * b_c * q2 + Nt * b_c * b_c;
    float mu = S1 / Nt;
    float var = S2 / Nt - mu * mu;
    float aa = gamma[c] / sqrtf(var + 1e-5f);
    sac[c] = aa;
    scc[c] = aa * (b_c - mu) + beta[c];
  }
  __syncthreads();

  const float* wbase = w1 + (size_t)o * (OCH * DN * DN);

  // pass A: float4 row loads, row stats from regs, stage to LDS (stride 21)
  for (int pair = tid; pair < OCH * DN; pair += 512) {
    int c = pair / DN, i = pair - c * DN;
    const float4* r = (const float4*)(wbase + pair * DN);
    float4 v0 = r[0], v1 = r[1], v2 = r[2], v3 = r[3], v4 = r[4];
    float first = v0.x, last = v4.w;
    float rs = v0.x + v0.y + v0.z + v0.w + v1.x + v1.y + v1.z + v1.w +
               v2.x + v2.y + v2.z + v2.w + v3.x + v3.y + v3.z + v3.w +
               v4.x + v4.y + v4.z + v4.w;
    float mid = rs - first - last;
#pragma unroll
    for (int p = 0; p < 3; ++p)
      rowRW[p][c][i] = first * swq[(c * 3 + p) * 3 + 0] +
                       mid   * swq[(c * 3 + p) * 3 + 1] +
                       last  * swq[(c * 3 + p) * 3 + 2];
    rowRS[c][i] = rs;
    float* dst = &sW[pair * 21];
    dst[0] = v0.x; dst[1] = v0.y; dst[2] = v0.z; dst[3] = v0.w;
    dst[4] = v1.x; dst[5] = v1.y; dst[6] = v1.z; dst[7] = v1.w;
    dst[8] = v2.x; dst[9] = v2.y; dst[10] = v2.z; dst[11] = v2.w;
    dst[12] = v3.x; dst[13] = v3.y; dst[14] = v3.z; dst[15] = v3.w;
    dst[16] = v4.x; dst[17] = v4.y; dst[18] = v4.z; dst[19] = v4.w;
  }
  __syncthreads();

  // pass B: col stats from LDS
  for (int pair = tid; pair < OCH * DN; pair += 512) {
    int c = pair / DN, j = pair - c * DN;
    const float* src = &sW[c * DN * 21 + j];
    float cs = 0.f, first = 0.f, last = 0.f;
#pragma unroll
    for (int i = 0; i < DN; ++i) {
      float vv = src[i * 21];
      cs += vv;
      if (i == 0) first = vv;
      if (i == DN - 1) last = vv;
    }
    float mid = cs - first - last;
#pragma unroll
    for (int q = 0; q < 3; ++q)
      colCW[q][c][j] = first * swp[(c * 3 + q) * 3 + 0] +
                       mid   * swp[(c * 3 + q) * 3 + 1] +
                       last  * swp[(c * 3 + q) * 3 + 2];
    colCS[c][j] = cs;
  }
  __syncthreads();

  if (tid < DK) {   // only a=0..3 matter downstream (d[a>=4]==0)
    int a = tid;
    float u = 0.f;
#pragma unroll
    for (int c = 0; c < OCH; ++c) {
      float plain = rowRS[c][a] + colCS[c][a];
      float m = rowRW[1][c][a] + colCW[1][c][a];
      m += rowRW[0][c][a + 1] + colCW[0][c][a + 1];
      if (a > 0) m += rowRW[2][c][a - 1] + colCW[2][c][a - 1];
      u += plain + sac[c] * m;
    }
    U4[o * DK + a] = u;
  } else if (tid >= 64 && tid < 64 + OCH) {
    int c = tid - 64;
    float s = 0.f;
#pragma unroll
    for (int i = 0; i < DN; ++i) s += rowRS[c][i];
    red[c] = scc[c] * s;
  }
  __syncthreads();
  if (tid == 0) {
    float s = 0.f;
#pragma unroll
    for (int c = 0; c < OCH; ++c) s += red[c];
    Cst[o] = b1[o] + s;
  }
}

// ---------- K3: fused FC1(rank-4)+ReLU+FC2, node-quad phase-2 ----------
#define NTN 16
__global__ __launch_bounds__(256, 4) void k_final(const float* __restrict__ dmat,
                                                  const float* __restrict__ U4,
                                                  const float* __restrict__ Cst,
                                                  const float* __restrict__ w2t,
                                                  const float* __restrict__ b2,
                                                  float* __restrict__ out, int n_node) {
  __shared__ float h1s[H1][20];        // 40 KB (cols 0..15 used)
  __shared__ float pacc[4][NTN][64];   // 16 KB
  int tid = threadIdx.x;
  int n0 = blockIdx.x * NTN;

  // ---- phase 1: h1s[k][node] = relu(Cst[k] + U4[k]·d4) ----
  {
    int node = tid & 15, kq = tid >> 4;
    float4 d4 = make_float4(0.f, 0.f, 0.f, 0.f);
    if (n0 + node < n_node)
      d4 = *(const float4*)(dmat + (size_t)(n0 + node) * DK);
    for (int k = kq; k < H1; k += 16) {
      float4 u4 = *(const float4*)(U4 + (size_t)k * DK);
      float z = Cst[k] + u4.x * d4.x + u4.y * d4.y + u4.z * d4.z + u4.w * d4.w;
      h1s[k][node] = fmaxf(z, 0.f);
    }
  }
  __syncthreads();

  // ---- phase 2 ----
  {
    int w = tid >> 6;
    int lane = tid & 63;
    int q = lane >> 4;          // node quad
    int og = lane & 15;         // outs og*4..og*4+3
    float a0x = 0.f, a0y = 0.f, a0z = 0.f, a0w = 0.f;
    float a1x = 0.f, a1y = 0.f, a1z = 0.f, a1w = 0.f;
    float a2x = 0.f, a2y = 0.f, a2z = 0.f, a2w = 0.f;
    float a3x = 0.f, a3y = 0.f, a3z = 0.f, a3w = 0.f;
    int k0 = w * 125, k1 = k0 + 125;
    for (int k = k0; k < k1; ++k) {
      float4 hv = *(const float4*)&h1s[k][q * 4];
      float4 wv = *(const float4*)(w2t + (size_t)k * 64 + og * 4);
      a0x += hv.x * wv.x; a0y += hv.x * wv.y; a0z += hv.x * wv.z; a0w += hv.x * wv.w;
      a1x += hv.y * wv.x; a1y += hv.y * wv.y; a1z += hv.y * wv.z; a1w += hv.y * wv.w;
      a2x += hv.z * wv.x; a2y += hv.z * wv.y; a2z += hv.z * wv.z; a2w += hv.z * wv.w;
      a3x += hv.w * wv.x; a3y += hv.w * wv.y; a3z += hv.w * wv.z; a3w += hv.w * wv.w;
    }
    *(float4*)&pacc[w][q * 4 + 0][og * 4] = make_float4(a0x, a0y, a0z, a0w);
    *(float4*)&pacc[w][q * 4 + 1][og * 4] = make_float4(a1x, a1y, a1z, a1w);
    *(float4*)&pacc[w][q * 4 + 2][og * 4] = make_float4(a2x, a2y, a2z, a2w);
    *(float4*)&pacc[w][q * 4 + 3][og * 4] = make_float4(a3x, a3y, a3z, a3w);
  }
  __syncthreads();

  for (int idx = tid; idx < NTN * H2; idx += 256) {
    int n = idx / H2, o = idx - n * H2;
    float vv = pacc[0][n][o] + pacc[1][n][o] + pacc[2][n][o] + pacc[3][n][o] + b2[o];
    if (n0 + n < n_node) out[(size_t)(n0 + n) * H2 + o] = vv;
  }
}

extern "C" void kernel_launch(void* const* d_in, const int* in_sizes, int n_in,
                              void* d_out, int out_size, void* d_ws, size_t ws_size,
                              hipStream_t stream) {
  const float* oe    = (const float*)d_in[0];
  const int*   nei   = (const int*)d_in[1];
  const int*   eai   = (const int*)d_in[2];
  const float* convw = (const float*)d_in[3];
  const float* convb = (const float*)d_in[4];
  const float* gamma = (const float*)d_in[5];
  const float* beta  = (const float*)d_in[6];
  const float* w1    = (const float*)d_in[7];
  const float* b1    = (const float*)d_in[8];
  const float* w2    = (const float*)d_in[9];
  const float* b2    = (const float*)d_in[10];
  float* out = (float*)d_out;
  float* ws  = (float*)d_ws;

  int n_node = in_sizes[2] / 2;

  float* dmat = ws + OFF_D;
  float* momp = ws + OFF_MOMP;
  float* wq   = ws + OFF_WQ;
  float* wp   = ws + OFF_WP;
  float* MT   = ws + OFF_MT;
  float* U4   = ws + OFF_U4;
  float* Cst  = ws + OFF_CST;
  float* w2t  = ws + OFF_W2T;

  int nbd = (n_node + NPB1 - 1) / NPB1;
  k_gd<<<nbd + 9, TB1, 0, stream>>>(oe, nei, eai, w2, convw,
                                    dmat, momp, w2t, wq, wp, MT, n_node);
  k_buildU<<<H1, 512, 0, stream>>>(w1, b1, convb, gamma, beta, wq, wp,
                                   momp, MT, nbd, n_node, U4, Cst);
  k_final<<<(n_node + NTN - 1) / NTN, 256, 0, stream>>>(dmat, U4, Cst, w2t, b2, out, n_node);
}

// Round 13
// 51.073 us; speedup vs baseline: 1.4500x; 1.4500x over previous
//
#include <hip/hip_runtime.h>
#include <hip/hip_bf16.h>
#include <math.h>

#define NFEAT 17
#define DN 20
#define OCH 32
#define H1 500
#define H2 60

// Only d[0..3] nonzero: g-rows are unit-norm positive => y=h[f] <= 2; grid step
// 2.632; max-normalized Gaussian at k>=4 underflows fp32 to 0.
#define DK 4

#define NPB 256   // nodes per gather block (2 thr/node, 512 thr)
#define NBW 64    // momp block-stride capacity (nbd = 8192/256 = 32)

// ws float offsets
#define OFF_D      0         // 8192*4 = 32768
#define OFF_MOMP   32768     // 14*64 = 896
#define OFF_MT     33664     // 32*14 = 448
#define OFF_PLAIN  34112     // 500*4 = 2000
#define OFF_M      36112     // 500*32*4 = 64000
#define OFF_RS     100112    // 500*32 = 16000
#define OFF_U4     116112    // 2000
#define OFF_CST    118112    // 512
#define OFF_W2T    118624    // 500*64 = 32000

// ---------------- K1: heterogeneous mega-kernel ----------------
// blocks [0,500):        w1 collapse -> plainU, M, rowsum   (independent of data)
// blocks [500,500+nbd):  gather+distribute+moment partials  (R11-verified logic)
// next 8 blocks:         w2 transpose -> w2t
// last block:            tap-moment MT (R12-verified math)
__global__ __launch_bounds__(512) void k_main(const float* __restrict__ oe,
                                              const int* __restrict__ nei,
                                              const int* __restrict__ eai,
                                              const float* __restrict__ w2,
                                              const float* __restrict__ convw,
                                              const float* __restrict__ w1,
                                              float* __restrict__ dmat,
                                              float* __restrict__ momp,
                                              float* __restrict__ w2t,
                                              float* __restrict__ MT,
                                              float* __restrict__ plainU,
                                              float* __restrict__ Mmat,
                                              float* __restrict__ rowsum,
                                              int n_node) {
  __shared__ float smem[19136];   // 76.5 KB union
  int tid = threadIdx.x;
  int nbd = (n_node + NPB - 1) / NPB;
  int bx = blockIdx.x;

  if (bx < H1) {
    // ---------- wstat for o = bx ----------
    float* sW    = smem;            // 13440  [pair][21]
    float* rowRS = sW + 13440;      // 640    [c*20+i]
    float* rowRW = rowRS + 640;     // 1920   [p*640 + c*20 + i]
    float* colCS = rowRW + 1920;    // 640
    float* colCW = colCS + 640;     // 1920   [q*640 + c*20 + j]
    float* swq   = colCW + 1920;    // 288
    float* swp   = swq + 288;       // 288
    if (tid < OCH) {
      int c = tid;
      float w[3][3];
#pragma unroll
      for (int p = 0; p < 3; ++p)
#pragma unroll
        for (int q = 0; q < 3; ++q) w[p][q] = convw[c * 9 + p * 3 + q];
#pragma unroll
      for (int p = 0; p < 3; ++p) {
        swq[(c * 3 + p) * 3 + 0] = w[p][1] + w[p][2];
        swq[(c * 3 + p) * 3 + 1] = w[p][0] + w[p][1] + w[p][2];
        swq[(c * 3 + p) * 3 + 2] = w[p][0] + w[p][1];
      }
#pragma unroll
      for (int q = 0; q < 3; ++q) {
        swp[(c * 3 + q) * 3 + 0] = w[1][q] + w[2][q];
        swp[(c * 3 + q) * 3 + 1] = w[0][q] + w[1][q] + w[2][q];
        swp[(c * 3 + q) * 3 + 2] = w[0][q] + w[1][q];
      }
    }
    __syncthreads();

    const float* wbase = w1 + (size_t)bx * (OCH * DN * DN);
    // pass A: float4 row loads, row stats, stage to LDS stride 21
    for (int pair = tid; pair < OCH * DN; pair += 512) {
      int c = pair / DN;
      const float4* r = (const float4*)(wbase + pair * DN);
      float4 v0 = r[0], v1 = r[1], v2 = r[2], v3 = r[3], v4 = r[4];
      float first = v0.x, last = v4.w;
      float rs = v0.x + v0.y + v0.z + v0.w + v1.x + v1.y + v1.z + v1.w +
                 v2.x + v2.y + v2.z + v2.w + v3.x + v3.y + v3.z + v3.w +
                 v4.x + v4.y + v4.z + v4.w;
      float mid = rs - first - last;
#pragma unroll
      for (int p = 0; p < 3; ++p)
        rowRW[p * 640 + pair] = first * swq[(c * 3 + p) * 3 + 0] +
                                mid   * swq[(c * 3 + p) * 3 + 1] +
                                last  * swq[(c * 3 + p) * 3 + 2];
      rowRS[pair] = rs;
      float* dst = &sW[pair * 21];
      dst[0] = v0.x; dst[1] = v0.y; dst[2] = v0.z; dst[3] = v0.w;
      dst[4] = v1.x; dst[5] = v1.y; dst[6] = v1.z; dst[7] = v1.w;
      dst[8] = v2.x; dst[9] = v2.y; dst[10] = v2.z; dst[11] = v2.w;
      dst[12] = v3.x; dst[13] = v3.y; dst[14] = v3.z; dst[15] = v3.w;
      dst[16] = v4.x; dst[17] = v4.y; dst[18] = v4.z; dst[19] = v4.w;
    }
    __syncthreads();
    // pass B: col stats from LDS
    for (int pair = tid; pair < OCH * DN; pair += 512) {
      int c = pair / DN, j = pair - c * DN;
      const float* src = &sW[c * DN * 21 + j];
      float cs = 0.f, first = 0.f, last = 0.f;
#pragma unroll
      for (int i = 0; i < DN; ++i) {
        float vv = src[i * 21];
        cs += vv;
        if (i == 0) first = vv;
        if (i == DN - 1) last = vv;
      }
      float mid = cs - first - last;
#pragma unroll
      for (int q = 0; q < 3; ++q)
        colCW[q * 640 + pair] = first * swp[(c * 3 + q) * 3 + 0] +
                                mid   * swp[(c * 3 + q) * 3 + 1] +
                                last  * swp[(c * 3 + q) * 3 + 2];
      colCS[pair] = cs;
    }
    __syncthreads();
    // outputs: M[o][c][a], rowsum[o][c], plainU[o][a]
    if (tid < 128) {
      int c = tid >> 2, a = tid & 3;
      float m = rowRW[640 + c * 20 + a] + colCW[640 + c * 20 + a]
              + rowRW[c * 20 + a + 1]   + colCW[c * 20 + a + 1];
      if (a > 0) m += rowRW[1280 + c * 20 + a - 1] + colCW[1280 + c * 20 + a - 1];
      Mmat[((size_t)bx * OCH + c) * 4 + a] = m;
    } else if (tid >= 128 && tid < 128 + OCH) {
      int c = tid - 128;
      float s = 0.f;
#pragma unroll
      for (int i = 0; i < DN; ++i) s += rowRS[c * 20 + i];
      rowsum[(size_t)bx * OCH + c] = s;
    } else if (tid >= 192 && tid < 192 + DK) {
      int a = tid - 192;
      float s = 0.f;
#pragma unroll
      for (int c = 0; c < OCH; ++c) s += rowRS[c * 20 + a] + colCS[c * 20 + a];
      plainU[bx * DK + a] = s;
    }
    return;
  }

  int rb = bx - H1;
  if (rb < nbd) {
    // ---------- gather + distribute block (R11 logic, 256 nodes) ----------
    float* dls = smem;   // [NPB][5] stride 5
    int nl = tid >> 1, half = tid & 1;
    int n = rb * NPB + nl;

    float v[NFEAT];
#pragma unroll
    for (int f = 0; f < NFEAT; ++f) v[f] = 0.f;
    if (n < n_node) {
      int e = eai[(size_t)n * 2 + half];
      float a4[NFEAT];
#pragma unroll
      for (int f = 0; f < NFEAT; ++f) a4[f] = 0.f;
#pragma unroll
      for (int m = 0; m < 4; ++m) {
        int at = nei[(size_t)e * 4 + m];
        const float* row = oe + (size_t)at * NFEAT;
#pragma unroll
        for (int f = 0; f < NFEAT; ++f) a4[f] += row[f];
      }
      float nrm = 0.f;
#pragma unroll
      for (int f = 0; f < NFEAT; ++f) { float t = a4[f] * 0.25f; a4[f] = t; nrm += t * t; }
      float inv = 1.0f / sqrtf(nrm);
#pragma unroll
      for (int f = 0; f < NFEAT; ++f) v[f] = a4[f] * inv;
    }
    float h[NFEAT];
#pragma unroll
    for (int f = 0; f < NFEAT; ++f) h[f] = v[f] + __shfl_xor(v[f], 1);

    const float step = 50.0f / 19.0f;
    const float inv2 = 1.0f / (2.0f * 0.3f * 0.3f);
    float s0 = 0.f, s1 = 0.f, s2 = 0.f, s3 = 0.f;
    int f0 = half ? 9 : 0, f1 = half ? NFEAT : 9;
    for (int f = f0; f < f1; ++f) {
      float y = h[f];
      if (!(y > 0.0f && y < 110.0f)) continue;
      float t0 = -y, t1 = step - y, t2 = 2.f * step - y, t3 = 3.f * step - y;
      float e0 = __expf(-t0 * t0 * inv2);
      float e1 = __expf(-t1 * t1 * inv2);
      float e2 = __expf(-t2 * t2 * inv2);
      float e3 = __expf(-t3 * t3 * inv2);
      float mx = fmaxf(fmaxf(e0, e1), fmaxf(e2, e3));
      if (mx > 0.f) {
        float im = 1.0f / mx;
        s0 += e0 * im; s1 += e1 * im; s2 += e2 * im; s3 += e3 * im;
      }
    }
    s0 += __shfl_xor(s0, 1); s1 += __shfl_xor(s1, 1);
    s2 += __shfl_xor(s2, 1); s3 += __shfl_xor(s3, 1);
    float smax = fmaxf(fmaxf(s0, s1), fmaxf(s2, s3));
    float ism = (smax > 0.f) ? 1.0f / smax : 1.0f;
    if (half == 0) {
      float d0 = s0 * ism, d1 = s1 * ism, d2 = s2 * ism, d3 = s3 * ism;
      dls[nl * 5 + 0] = d0; dls[nl * 5 + 1] = d1;
      dls[nl * 5 + 2] = d2; dls[nl * 5 + 3] = d3;
      if (n < n_node)
        *(float4*)(dmat + (size_t)n * DK) = make_float4(d0, d1, d2, d3);
    }
    __syncthreads();
    if (tid < 14) {
      int u = tid;
      float acc = 0.f;
      if (u < 10) {
        int aa = 0, rem = u;
        while (rem >= DK - aa) { rem -= DK - aa; ++aa; }
        int bb = aa + rem;
        for (int l = 0; l < NPB; ++l) acc += dls[l * 5 + aa] * dls[l * 5 + bb];
      } else {
        int aa = u - 10;
        for (int l = 0; l < NPB; ++l) acc += dls[l * 5 + aa];
      }
      momp[(size_t)u * NBW + rb] = acc;
    }
    return;
  }

  int tb = rb - nbd;
  if (tb < 8) {
    // ---------- coalesced w2 transpose slab ----------
    float (*sT)[61] = (float(*)[61])smem;
    int o0 = tb * 64;
    int lo = tid & 63, jr = tid >> 6;
    for (int j = jr; j < H2; j += 8)
      if (o0 + lo < H1) sT[lo][j] = w2[(size_t)j * H1 + o0 + lo];
    __syncthreads();
    int jj = tid & 63, orr = tid >> 6;
    for (int ol = orr; ol < 64; ol += 8) {
      int o = o0 + ol;
      if (o < H1) w2t[(size_t)o * 64 + jj] = (jj < H2) ? sT[ol][jj] : 0.f;
    }
    return;
  }

  // ---------- tap-moment MT block (R12-verified) ----------
  {
    float* swqL = smem;          // 288
    float* swpL = smem + 288;    // 288
    float* MTs  = smem + 576;    // [32][14]
    if (tid < OCH) {
      int c = tid;
      float w[3][3];
#pragma unroll
      for (int p = 0; p < 3; ++p)
#pragma unroll
        for (int q = 0; q < 3; ++q) w[p][q] = convw[c * 9 + p * 3 + q];
#pragma unroll
      for (int p = 0; p < 3; ++p) {
        swqL[(c * 3 + p) * 3 + 0] = w[p][1] + w[p][2];
        swqL[(c * 3 + p) * 3 + 1] = w[p][0] + w[p][1] + w[p][2];
        swqL[(c * 3 + p) * 3 + 2] = w[p][0] + w[p][1];
      }
#pragma unroll
      for (int q = 0; q < 3; ++q) {
        swpL[(c * 3 + q) * 3 + 0] = w[1][q] + w[2][q];
        swpL[(c * 3 + q) * 3 + 1] = w[0][q] + w[1][q] + w[2][q];
        swpL[(c * 3 + q) * 3 + 2] = w[0][q] + w[1][q];
      }
    }
    for (int idx = tid; idx < OCH * 14; idx += 512) MTs[idx] = 0.f;
    __syncthreads();
    int c = tid & 31, grp = tid >> 5;   // 16 position groups
    float wqr[3][3], wpr[3][3];
#pragma unroll
    for (int p = 0; p < 3; ++p)
#pragma unroll
      for (int k = 0; k < 3; ++k) {
        wqr[p][k] = swqL[(c * 3 + p) * 3 + k];
        wpr[p][k] = swpL[(c * 3 + p) * 3 + k];
      }
    float T0 = 0, T1 = 0, T2 = 0, T3 = 0;
    float M0 = 0, M1 = 0, M2 = 0, M3 = 0, M4 = 0, M5 = 0, M6 = 0, M7 = 0, M8 = 0, M9 = 0;
    for (int pos = grp; pos < DN * DN; pos += 16) {
      int i = pos / DN, j = pos - (pos / DN) * DN;
      int icls = (i == 0) ? 0 : ((i == DN - 1) ? 2 : 1);
      int jcls = (j == 0) ? 0 : ((j == DN - 1) ? 2 : 1);
      float t0 = 0, t1 = 0, t2 = 0, t3 = 0;
      int p;
      p = 0 - i + 1; if ((unsigned)p <= 2u) t0 += wqr[p][jcls];
      p = 1 - i + 1; if ((unsigned)p <= 2u) t1 += wqr[p][jcls];
      p = 2 - i + 1; if ((unsigned)p <= 2u) t2 += wqr[p][jcls];
      p = 3 - i + 1; if ((unsigned)p <= 2u) t3 += wqr[p][jcls];
      p = 0 - j + 1; if ((unsigned)p <= 2u) t0 += wpr[p][icls];
      p = 1 - j + 1; if ((unsigned)p <= 2u) t1 += wpr[p][icls];
      p = 2 - j + 1; if ((unsigned)p <= 2u) t2 += wpr[p][icls];
      p = 3 - j + 1; if ((unsigned)p <= 2u) t3 += wpr[p][icls];
      T0 += t0; T1 += t1; T2 += t2; T3 += t3;
      M0 += t0 * t0; M1 += t0 * t1; M2 += t0 * t2; M3 += t0 * t3;
      M4 += t1 * t1; M5 += t1 * t2; M6 += t1 * t3;
      M7 += t2 * t2; M8 += t2 * t3; M9 += t3 * t3;
    }
    atomicAdd(&MTs[c * 14 + 0], T0); atomicAdd(&MTs[c * 14 + 1], T1);
    atomicAdd(&MTs[c * 14 + 2], T2); atomicAdd(&MTs[c * 14 + 3], T3);
    atomicAdd(&MTs[c * 14 + 4], M0); atomicAdd(&MTs[c * 14 + 5], M1);
    atomicAdd(&MTs[c * 14 + 6], M2); atomicAdd(&MTs[c * 14 + 7], M3);
    atomicAdd(&MTs[c * 14 + 8], M4); atomicAdd(&MTs[c * 14 + 9], M5);
    atomicAdd(&MTs[c * 14 + 10], M6); atomicAdd(&MTs[c * 14 + 11], M7);
    atomicAdd(&MTs[c * 14 + 12], M8); atomicAdd(&MTs[c * 14 + 13], M9);
    __syncthreads();
    for (int idx = tid; idx < OCH * 14; idx += 512) MT[idx] = MTs[idx];
  }
}

// ---------------- K2: coefs + U4/Cst assembly (8 blocks) ----------------
__global__ __launch_bounds__(512) void k_combine(const float* __restrict__ momp,
                                                 const float* __restrict__ MT,
                                                 const float* __restrict__ convb,
                                                 const float* __restrict__ gamma,
                                                 const float* __restrict__ beta,
                                                 const float* __restrict__ b1,
                                                 const float* __restrict__ plainU,
                                                 const float* __restrict__ Mmat,
                                                 const float* __restrict__ rowsum,
                                                 int nbd, int n_node,
                                                 float* __restrict__ U4,
                                                 float* __restrict__ Cst) {
  __shared__ float sac[OCH], scc[OCH], phat[10], S4[4], mred[14];
  int tid = threadIdx.x;
  if (tid < 14) {
    float acc = 0.f;
    const float* mp = momp + (size_t)tid * NBW;
    for (int b = 0; b < nbd; ++b) acc += mp[b];
    mred[tid] = acc;
  }
  __syncthreads();
  if (tid < 14) {
    float vv = mred[tid];
    if (tid < 10) {
      int aa = 0, rem = tid;
      while (rem >= DK - aa) { rem -= DK - aa; ++aa; }
      int bb = aa + rem;
      phat[tid] = (aa == bb ? 1.f : 2.f) * vv;
    } else {
      S4[tid - 10] = vv;
    }
  }
  __syncthreads();
  if (tid < OCH) {
    int c = tid;
    const float* mt = MT + c * 14;
    float q2 = mt[0] * S4[0] + mt[1] * S4[1] + mt[2] * S4[2] + mt[3] * S4[3];
    float q1 = 0.f;
#pragma unroll
    for (int u = 0; u < 10; ++u) q1 += mt[4 + u] * phat[u];
    float b_c = convb[c];
    float Nt = (float)n_node * 400.f;
    float S1 = q2 + Nt * b_c;
    float S2 = q1 + 2.f * b_c * q2 + Nt * b_c * b_c;
    float mu = S1 / Nt;
    float var = S2 / Nt - mu * mu;
    float aa = gamma[c] / sqrtf(var + 1e-5f);
    sac[c] = aa;
    scc[c] = aa * (b_c - mu) + beta[c];
  }
  __syncthreads();

  int o0 = blockIdx.x * 63;
  for (int idx = tid; idx < 63 * DK; idx += 512) {
    int ol = idx >> 2, a = idx & 3;
    int o = o0 + ol;
    if (o < H1) {
      float u = plainU[o * DK + a];
      const float* mrow = Mmat + (size_t)o * (OCH * 4) + a;
#pragma unroll
      for (int c = 0; c < OCH; ++c) u += sac[c] * mrow[c * 4];
      U4[o * DK + a] = u;
    }
  }
  if (tid < 63) {
    int o = o0 + tid;
    if (o < H1) {
      float s = b1[o];
      const float* rr = rowsum + (size_t)o * OCH;
#pragma unroll
      for (int c = 0; c < OCH; ++c) s += scc[c] * rr[c];
      Cst[o] = s;
    }
  }
}

// ---------------- K3: fused FC1(rank-4)+ReLU+FC2 (verified) ----------------
#define NTN 16
__global__ __launch_bounds__(256, 4) void k_final(const float* __restrict__ dmat,
                                                  const float* __restrict__ U4,
                                                  const float* __restrict__ Cst,
                                                  const float* __restrict__ w2t,
                                                  const float* __restrict__ b2,
                                                  float* __restrict__ out, int n_node) {
  __shared__ float h1s[H1][20];
  __shared__ float pacc[4][NTN][64];
  int tid = threadIdx.x;
  int n0 = blockIdx.x * NTN;

  {
    int node = tid & 15, kq = tid >> 4;
    float4 d4 = make_float4(0.f, 0.f, 0.f, 0.f);
    if (n0 + node < n_node)
      d4 = *(const float4*)(dmat + (size_t)(n0 + node) * DK);
    for (int k = kq; k < H1; k += 16) {
      float4 u4 = *(const float4*)(U4 + (size_t)k * DK);
      float z = Cst[k] + u4.x * d4.x + u4.y * d4.y + u4.z * d4.z + u4.w * d4.w;
      h1s[k][node] = fmaxf(z, 0.f);
    }
  }
  __syncthreads();

  {
    int w = tid >> 6;
    int lane = tid & 63;
    int q = lane >> 4;
    int og = lane & 15;
    float a0x = 0.f, a0y = 0.f, a0z = 0.f, a0w = 0.f;
    float a1x = 0.f, a1y = 0.f, a1z = 0.f, a1w = 0.f;
    float a2x = 0.f, a2y = 0.f, a2z = 0.f, a2w = 0.f;
    float a3x = 0.f, a3y = 0.f, a3z = 0.f, a3w = 0.f;
    int k0 = w * 125, k1 = k0 + 125;
    for (int k = k0; k < k1; ++k) {
      float4 hv = *(const float4*)&h1s[k][q * 4];
      float4 wv = *(const float4*)(w2t + (size_t)k * 64 + og * 4);
      a0x += hv.x * wv.x; a0y += hv.x * wv.y; a0z += hv.x * wv.z; a0w += hv.x * wv.w;
      a1x += hv.y * wv.x; a1y += hv.y * wv.y; a1z += hv.y * wv.z; a1w += hv.y * wv.w;
      a2x += hv.z * wv.x; a2y += hv.z * wv.y; a2z += hv.z * wv.z; a2w += hv.z * wv.w;
      a3x += hv.w * wv.x; a3y += hv.w * wv.y; a3z += hv.w * wv.z; a3w += hv.w * wv.w;
    }
    *(float4*)&pacc[w][q * 4 + 0][og * 4] = make_float4(a0x, a0y, a0z, a0w);
    *(float4*)&pacc[w][q * 4 + 1][og * 4] = make_float4(a1x, a1y, a1z, a1w);
    *(float4*)&pacc[w][q * 4 + 2][og * 4] = make_float4(a2x, a2y, a2z, a2w);
    *(float4*)&pacc[w][q * 4 + 3][og * 4] = make_float4(a3x, a3y, a3z, a3w);
  }
  __syncthreads();

  for (int idx = tid; idx < NTN * H2; idx += 256) {
    int n = idx / H2, o = idx - n * H2;
    float vv = pacc[0][n][o] + pacc[1][n][o] + pacc[2][n][o] + pacc[3][n][o] + b2[o];
    if (n0 + n < n_node) out[(size_t)(n0 + n) * H2 + o] = vv;
  }
}

extern "C" void kernel_launch(void* const* d_in, const int* in_sizes, int n_in,
                              void* d_out, int out_size, void* d_ws, size_t ws_size,
                              hipStream_t stream) {
  const float* oe    = (const float*)d_in[0];
  const int*   nei   = (const int*)d_in[1];
  const int*   eai   = (const int*)d_in[2];
  const float* convw = (const float*)d_in[3];
  const float* convb = (const float*)d_in[4];
  const float* gamma = (const float*)d_in[5];
  const float* beta  = (const float*)d_in[6];
  const float* w1    = (const float*)d_in[7];
  const float* b1    = (const float*)d_in[8];
  const float* w2    = (const float*)d_in[9];
  const float* b2    = (const float*)d_in[10];
  float* out = (float*)d_out;
  float* ws  = (float*)d_ws;

  int n_node = in_sizes[2] / 2;

  float* dmat   = ws + OFF_D;
  float* momp   = ws + OFF_MOMP;
  float* MT     = ws + OFF_MT;
  float* plainU = ws + OFF_PLAIN;
  float* Mmat   = ws + OFF_M;
  float* rowsum = ws + OFF_RS;
  float* U4     = ws + OFF_U4;
  float* Cst    = ws + OFF_CST;
  float* w2t    = ws + OFF_W2T;

  int nbd = (n_node + NPB - 1) / NPB;
  k_main<<<H1 + nbd + 9, 512, 0, stream>>>(oe, nei, eai, w2, convw, w1,
                                           dmat, momp, w2t, MT,
                                           plainU, Mmat, rowsum, n_node);
  k_combine<<<8, 512, 0, stream>>>(momp, MT, convb, gamma, beta, b1,
                                   plainU, Mmat, rowsum, nbd, n_node, U4, Cst);
  k_final<<<(n_node + NTN - 1) / NTN, 256, 0, stream>>>(dmat, U4, Cst, w2t, b2, out, n_node);
}